// Round 3
// baseline (1095.120 us; speedup 1.0000x reference)
//
#include <hip/hip_runtime.h>
#include <hip/hip_bf16.h>

#define S_LEN 2048
#define DIM   1024
#define NH    16
#define KVH   4
#define HD    64
#define KVDIM 256
#define INNER 2048
#define NSTATE 16
#define DTR   64
#define FUSED_N 4608   // 2*KVDIM + 2*INNER

typedef __attribute__((ext_vector_type(8))) short short8;
typedef __attribute__((ext_vector_type(4))) float f32x4;
typedef __hip_bfloat16 bf16;

__device__ inline short f2bs(float x) {
  bf16 h = __float2bfloat16(x);
  return *reinterpret_cast<short*>(&h);
}

// ---------------------------------------------------------------------------
// fp32 -> bf16 cast (pre-stage for MFMA operands)
// ---------------------------------------------------------------------------
__global__ __launch_bounds__(256) void cast_f2b(const float* __restrict__ src,
                                                short* __restrict__ dst, int n) {
  int i = blockIdx.x * 256 + threadIdx.x;
  if (i < n) dst[i] = f2bs(src[i]);
}

// ---------------------------------------------------------------------------
// C = A (MxK, bf16 row-major) * B^T (B is NxK bf16 row-major) -> C MxN (fp32)
// 64x64 tile, BK=32, 4 waves of 2x2 16x16x32 MFMA tiles.
// LDS in fragment order [kq][row][8] so ds_read_b128 is conflict-free.
// M multiple of 64, K multiple of 32; N arbitrary (guarded).
// ---------------------------------------------------------------------------
__global__ __launch_bounds__(256) void gemm_bt(const short* __restrict__ A,
                                               const short* __restrict__ B,
                                               float* __restrict__ C,
                                               int M, int N, int K) {
  __shared__ short As[4][64][8];
  __shared__ short Bs[4][64][8];
  const int tid = threadIdx.x;
  const int bm = blockIdx.x * 64;
  const int bn = blockIdx.y * 64;
  const int wid = tid >> 6;
  const int lane = tid & 63;
  const int wm = (wid >> 1) * 32;
  const int wn = (wid & 1) * 32;
  const int m16 = lane & 15;
  const int quad = lane >> 4;
  const int lrow = tid >> 2;
  const int lkq = tid & 3;

  f32x4 acc[2][2];
  #pragma unroll
  for (int i = 0; i < 2; ++i)
    #pragma unroll
    for (int j = 0; j < 2; ++j) acc[i][j] = f32x4{0.f, 0.f, 0.f, 0.f};

  const short* aptr = A + (size_t)(bm + lrow) * K + lkq * 8;
  const bool bvalid = (bn + lrow) < N;
  const short* bptr = B + (size_t)(bn + lrow) * K + lkq * 8;

  for (int k0 = 0; k0 < K; k0 += 32) {
    short8 av = *reinterpret_cast<const short8*>(aptr + k0);
    short8 bv = {0, 0, 0, 0, 0, 0, 0, 0};
    if (bvalid) bv = *reinterpret_cast<const short8*>(bptr + k0);
    __syncthreads();  // previous iteration's LDS reads complete
    *reinterpret_cast<short8*>(&As[lkq][lrow][0]) = av;
    *reinterpret_cast<short8*>(&Bs[lkq][lrow][0]) = bv;
    __syncthreads();
    short8 a0 = *reinterpret_cast<const short8*>(&As[quad][wm + m16][0]);
    short8 a1 = *reinterpret_cast<const short8*>(&As[quad][wm + 16 + m16][0]);
    short8 b0 = *reinterpret_cast<const short8*>(&Bs[quad][wn + m16][0]);
    short8 b1 = *reinterpret_cast<const short8*>(&Bs[quad][wn + 16 + m16][0]);
    acc[0][0] = __builtin_amdgcn_mfma_f32_16x16x32_bf16(a0, b0, acc[0][0], 0, 0, 0);
    acc[0][1] = __builtin_amdgcn_mfma_f32_16x16x32_bf16(a0, b1, acc[0][1], 0, 0, 0);
    acc[1][0] = __builtin_amdgcn_mfma_f32_16x16x32_bf16(a1, b0, acc[1][0], 0, 0, 0);
    acc[1][1] = __builtin_amdgcn_mfma_f32_16x16x32_bf16(a1, b1, acc[1][1], 0, 0, 0);
  }

  // C/D layout: col = lane&15, row = quad*4 + reg   [verified m89/m91]
  const int r0 = bm + wm + quad * 4;
  const int c0 = bn + wn + m16;
  #pragma unroll
  for (int ti = 0; ti < 2; ++ti) {
    #pragma unroll
    for (int tj = 0; tj < 2; ++tj) {
      int cc = c0 + tj * 16;
      if (cc >= N) continue;
      #pragma unroll
      for (int i = 0; i < 4; ++i) {
        int rr = r0 + ti * 16 + i;
        C[(size_t)rr * N + cc] = acc[ti][tj][i];
      }
    }
  }
}

// ---------------------------------------------------------------------------
// Per (s, head): RMS norm (64-dim), RoPE on first 32 dims, scale+gain for q.
// Also copies v (kv heads). Emits bf16 in [head][s][64] layout.
// blockDim = 64 (one wave), grid (S, NH+KVH).
// ---------------------------------------------------------------------------
__global__ __launch_bounds__(64) void qkv_prep(const float* __restrict__ q_out,
                                               const float* __restrict__ fused,
                                               const float* __restrict__ q_gain,
                                               short* __restrict__ qh,
                                               short* __restrict__ kh,
                                               short* __restrict__ vh) {
  const int s = blockIdx.x;
  const int hh = blockIdx.y;  // 0..NH-1 = q heads, NH..NH+KVH-1 = k heads
  const int lane = threadIdx.x;

  float val;
  if (hh < NH) val = q_out[(size_t)s * DIM + hh * HD + lane];
  else         val = fused[(size_t)s * FUSED_N + (hh - NH) * HD + lane];

  float sq = val * val;
  #pragma unroll
  for (int off = 32; off >= 1; off >>= 1) sq += __shfl_xor(sq, off);
  float r = rsqrtf(sq * (1.0f / 64.0f) + 1.1920929e-07f);  // FLT_EPSILON
  float v2 = val * r;

  float partner = __shfl_xor(v2, 16);
  if (lane < 32) {
    int fi = lane & 15;
    // inv_freq = 10000^(-fi/16)
    float inv = expf(-(float)fi * (9.210340371976184f / 16.0f));
    float ang = (float)s * inv;
    float sn, c;
    sincosf(ang, &sn, &c);
    v2 = (lane < 16) ? (v2 * c + partner * sn) : (v2 * c - partner * sn);
  }

  if (hh < NH) {
    v2 *= 0.125f * q_gain[hh];  // fold 1/sqrt(HD) and gain
    qh[((size_t)hh * S_LEN + s) * HD + lane] = f2bs(v2);
  } else {
    int kv = hh - NH;
    kh[((size_t)kv * S_LEN + s) * HD + lane] = f2bs(v2);
    float vv = fused[(size_t)s * FUSED_N + KVDIM + kv * HD + lane];
    vh[((size_t)kv * S_LEN + s) * HD + lane] = f2bs(vv);
  }
}

// ---------------------------------------------------------------------------
// Flash attention, MFMA. Block = 64 q-rows of one head; 4 waves x 16 rows.
// ---------------------------------------------------------------------------
__global__ __launch_bounds__(256) void attn_kernel(const short* __restrict__ qh,
                                                   const short* __restrict__ kh,
                                                   const short* __restrict__ vh,
                                                   float* __restrict__ attn_out) {
  __shared__ short Ks[32][72];      // 32 keys x 64 dims, padded
  __shared__ short Vt[64][40];      // 64 dims x 32 keys, padded
  __shared__ short Ps[4][16][40];   // per-wave P: 16 rows x 32 keys, padded

  const int tid = threadIdx.x;
  const int wv = tid >> 6;
  const int lane = tid & 63;
  const int qt = blockIdx.x;
  const int h = blockIdx.y;
  const int kvh = h >> 2;           // H/KVH = 4
  const int m16 = lane & 15;
  const int quad = lane >> 4;
  const int qrow0 = qt * 64 + wv * 16;

  // Q fragments: A-operand layout A[m=lane&15][k=quad*8+j]
  const short* qptr = qh + ((size_t)h * S_LEN + qrow0 + m16) * HD;
  short8 qf0 = *reinterpret_cast<const short8*>(qptr + quad * 8);
  short8 qf1 = *reinterpret_cast<const short8*>(qptr + 32 + quad * 8);

  f32x4 o[4];
  float mrow[4], lrow[4];
  #pragma unroll
  for (int i = 0; i < 4; ++i) {
    o[i] = f32x4{0.f, 0.f, 0.f, 0.f};
    mrow[i] = -1e30f;
    lrow[i] = 0.f;
  }

  const int ntiles = qt * 2 + 2;
  const int ldr = tid >> 3;          // 0..31 key row
  const int ldc = (tid & 7) * 8;     // dim chunk
  const short* kbase = kh + (size_t)kvh * S_LEN * HD;
  const short* vbase = vh + (size_t)kvh * S_LEN * HD;

  for (int jt = 0; jt < ntiles; ++jt) {
    const int key0 = jt * 32;
    short8 kv8 = *reinterpret_cast<const short8*>(kbase + (size_t)(key0 + ldr) * HD + ldc);
    short8 vv8 = *reinterpret_cast<const short8*>(vbase + (size_t)(key0 + ldr) * HD + ldc);
    __syncthreads();
    *reinterpret_cast<short8*>(&Ks[ldr][ldc]) = kv8;
    #pragma unroll
    for (int i = 0; i < 8; ++i) Vt[ldc + i][ldr] = vv8[i];  // transpose V
    __syncthreads();

    // scores: 2 sub-tiles of 16 keys
    f32x4 sc[2];
    #pragma unroll
    for (int sub = 0; sub < 2; ++sub) {
      short8 kf0 = *reinterpret_cast<const short8*>(&Ks[sub * 16 + m16][quad * 8]);
      short8 kf1 = *reinterpret_cast<const short8*>(&Ks[sub * 16 + m16][32 + quad * 8]);
      f32x4 z = f32x4{0.f, 0.f, 0.f, 0.f};
      z = __builtin_amdgcn_mfma_f32_16x16x32_bf16(qf0, kf0, z, 0, 0, 0);
      z = __builtin_amdgcn_mfma_f32_16x16x32_bf16(qf1, kf1, z, 0, 0, 0);
      sc[sub] = z;
    }

    // online softmax per row (C layout: row = quad*4+i, col/key = m16)
    #pragma unroll
    for (int i = 0; i < 4; ++i) {
      const int qpos = qrow0 + quad * 4 + i;
      float s0 = (key0 + m16 <= qpos) ? sc[0][i] : -1e30f;
      float s1 = (key0 + 16 + m16 <= qpos) ? sc[1][i] : -1e30f;
      float rm = fmaxf(s0, s1);
      rm = fmaxf(rm, __shfl_xor(rm, 1));
      rm = fmaxf(rm, __shfl_xor(rm, 2));
      rm = fmaxf(rm, __shfl_xor(rm, 4));
      rm = fmaxf(rm, __shfl_xor(rm, 8));
      float mnew = fmaxf(mrow[i], rm);
      float alpha = __expf(mrow[i] - mnew);
      float p0 = __expf(s0 - mnew);
      float p1 = __expf(s1 - mnew);
      float rs = p0 + p1;
      rs += __shfl_xor(rs, 1);
      rs += __shfl_xor(rs, 2);
      rs += __shfl_xor(rs, 4);
      rs += __shfl_xor(rs, 8);
      lrow[i] = lrow[i] * alpha + rs;
      mrow[i] = mnew;
      #pragma unroll
      for (int nc = 0; nc < 4; ++nc) o[nc][i] *= alpha;
      Ps[wv][quad * 4 + i][m16] = f2bs(p0);
      Ps[wv][quad * 4 + i][16 + m16] = f2bs(p1);
    }
    __syncthreads();  // P stores visible before fragment reload

    // PV: P enters as A-operand
    short8 af = *reinterpret_cast<const short8*>(&Ps[wv][m16][quad * 8]);
    #pragma unroll
    for (int nc = 0; nc < 4; ++nc) {
      short8 bfv = *reinterpret_cast<const short8*>(&Vt[nc * 16 + m16][quad * 8]);
      o[nc] = __builtin_amdgcn_mfma_f32_16x16x32_bf16(af, bfv, o[nc], 0, 0, 0);
    }
  }

  #pragma unroll
  for (int i = 0; i < 4; ++i) {
    float inv_l = 1.0f / lrow[i];
    int rr = qrow0 + quad * 4 + i;
    #pragma unroll
    for (int nc = 0; nc < 4; ++nc)
      attn_out[(size_t)rr * DIM + h * HD + nc * 16 + m16] = o[nc][i] * inv_l;
  }
}

// ---------------------------------------------------------------------------
// Depthwise causal conv (K=4) + bias + SiLU. One thread per (s, c).
// ---------------------------------------------------------------------------
__global__ __launch_bounds__(256) void conv_kernel(const float* __restrict__ fused,
                                                   const float* __restrict__ conv_w,
                                                   const float* __restrict__ conv_b,
                                                   float* __restrict__ xs_f32,
                                                   short* __restrict__ xs_b) {
  const int c = blockIdx.x * 256 + threadIdx.x;
  const int s = blockIdx.y;
  float acc = conv_b[c];
  #pragma unroll
  for (int t = 0; t < 4; ++t) {
    int sp = s - 3 + t;
    if (sp >= 0)
      acc += fused[(size_t)sp * FUSED_N + 2 * KVDIM + c] * conv_w[c * 4 + t];
  }
  float sv = acc / (1.f + __expf(-acc));  // silu
  xs_f32[(size_t)s * INNER + c] = sv;
  xs_b[(size_t)s * INNER + c] = f2bs(sv);
}

__global__ __launch_bounds__(256) void cast_dtlow(const float* __restrict__ ssm,
                                                  short* __restrict__ dtlow) {
  const int i = blockIdx.x * 256 + threadIdx.x;  // < S*DTR
  const int row = i >> 6, col = i & 63;
  dtlow[i] = f2bs(ssm[(size_t)row * 96 + col]);
}

__global__ __launch_bounds__(256) void delta_kernel(float* __restrict__ dt,
                                                    const float* __restrict__ b_dt) {
  const size_t i = (size_t)blockIdx.x * 256 + threadIdx.x;
  const int dcol = (int)(i & (INNER - 1));
  float xv = dt[i] + b_dt[dcol];
  dt[i] = (xv > 20.f) ? xv : log1pf(__expf(xv));  // softplus, in place
}

// ---------------------------------------------------------------------------
// Sequential selective scan. Block = 16 channels x 16 states; chunked LDS
// staging of 64 timesteps. Fuses D-term + gate SiLU.
// ---------------------------------------------------------------------------
__global__ __launch_bounds__(256) void scan_kernel(const float* __restrict__ delta,
                                                   const float* __restrict__ xs,
                                                   const float* __restrict__ ssm,
                                                   const float* __restrict__ fused,
                                                   const float* __restrict__ A_log,
                                                   const float* __restrict__ D_param,
                                                   short* __restrict__ scan_out) {
  __shared__ float Ld[64][16], Lu[64][16], Lg[64][16], Lb[64][16], Lc[64][16];
  const int tid = threadIdx.x;
  const int nl = tid & 15;        // state index
  const int dl = tid >> 4;        // local channel (16 per block)
  const int d0 = blockIdx.x * 16;
  const int d = d0 + dl;
  const float Aa = -__expf(A_log[(size_t)d * NSTATE + nl]);
  const float Dp = D_param[d];
  float h = 0.f;

  for (int s0 = 0; s0 < S_LEN; s0 += 64) {
    __syncthreads();
    #pragma unroll
    for (int rep = 0; rep < 4; ++rep) {
      int f = tid + rep * 256;
      int sl = f >> 4, dc = f & 15;
      int sg = s0 + sl;
      Ld[sl][dc] = delta[(size_t)sg * INNER + d0 + dc];
      Lu[sl][dc] = xs[(size_t)sg * INNER + d0 + dc];
      Lg[sl][dc] = fused[(size_t)sg * FUSED_N + 2 * KVDIM + INNER + d0 + dc];
      Lb[sl][dc] = ssm[(size_t)sg * 96 + DTR + dc];
      Lc[sl][dc] = ssm[(size_t)sg * 96 + DTR + NSTATE + dc];
    }
    __syncthreads();
    for (int sl = 0; sl < 64; ++sl) {
      float dlt = Ld[sl][dl];
      float u = Lu[sl][dl];
      float Bv = Lb[sl][nl];
      float Cv = Lc[sl][nl];
      h = __expf(dlt * Aa) * h + (dlt * u) * Bv;
      float t = h * Cv;
      t += __shfl_xor(t, 1);
      t += __shfl_xor(t, 2);
      t += __shfl_xor(t, 4);
      t += __shfl_xor(t, 8);
      if (nl == 0) {
        float g = Lg[sl][dl];
        float scv = (t + u * Dp) * (g / (1.f + __expf(-g)));
        scan_out[(size_t)(s0 + sl) * INNER + d] = f2bs(scv);
      }
    }
  }
}

__global__ __launch_bounds__(256) void merge_kernel(const float* __restrict__ attn_out,
                                                    const float* __restrict__ mamba_out,
                                                    const float* __restrict__ merge_alpha,
                                                    short* __restrict__ merged) {
  const size_t i = (size_t)blockIdx.x * 256 + threadIdx.x;
  float a = merge_alpha[0];
  float w = 1.f / (1.f + __expf(-a));
  merged[i] = f2bs(w * attn_out[i] + (1.f - w) * mamba_out[i]);
}

// ---------------------------------------------------------------------------
extern "C" void kernel_launch(void* const* d_in, const int* in_sizes, int n_in,
                              void* d_out, int out_size, void* d_ws, size_t ws_size,
                              hipStream_t stream) {
  const float* x       = (const float*)d_in[0];
  const float* W_cq    = (const float*)d_in[1];
  const float* W_in    = (const float*)d_in[2];
  const float* q_gain  = (const float*)d_in[3];
  const float* conv_w  = (const float*)d_in[4];
  const float* conv_b  = (const float*)d_in[5];
  const float* W_xproj = (const float*)d_in[6];
  const float* W_dt    = (const float*)d_in[7];
  const float* b_dt    = (const float*)d_in[8];
  const float* A_log   = (const float*)d_in[9];
  const float* D_param = (const float*)d_in[10];
  const float* W_mout  = (const float*)d_in[11];
  const float* W_proj  = (const float*)d_in[12];
  const float* merge_a = (const float*)d_in[13];

  char* p = (char*)d_ws;
  auto alloc = [&](size_t bytes) {
    char* r = p;
    p += (bytes + 255) & ~(size_t)255;
    return r;
  };
  // bf16 copies of MFMA operands
  short* xb     = (short*)alloc((size_t)S_LEN * DIM * 2);       // 4 MB
  short* Wcq_b  = (short*)alloc((size_t)DIM * DIM * 2);         // 2 MB
  short* Win_b  = (short*)alloc((size_t)FUSED_N * DIM * 2);     // 9.4 MB
  short* Wxp_b  = (short*)alloc((size_t)96 * INNER * 2);        // 0.4 MB
  short* Wdt_b  = (short*)alloc((size_t)INNER * DTR * 2);       // 0.26 MB
  short* Wmo_b  = (short*)alloc((size_t)DIM * INNER * 2);       // 4 MB
  short* Wpr_b  = (short*)alloc((size_t)DIM * DIM * 2);         // 2 MB
  // fp32 intermediates
  float* q_out  = (float*)alloc((size_t)S_LEN * DIM * 4);       // 8 MB (reused as attn_out)
  float* fusedb = (float*)alloc((size_t)S_LEN * FUSED_N * 4);   // 36 MB
  short* qh     = (short*)alloc((size_t)NH * S_LEN * HD * 2);   // 4 MB (reused as merged)
  short* kh     = (short*)alloc((size_t)KVH * S_LEN * HD * 2);  // 1 MB
  short* vh     = (short*)alloc((size_t)KVH * S_LEN * HD * 2);  // 1 MB
  float* xsf    = (float*)alloc((size_t)S_LEN * INNER * 4);     // 16 MB
  short* xsb    = (short*)alloc((size_t)S_LEN * INNER * 2);     // 8 MB (reused as scan_out)
  float* ssmp   = (float*)alloc((size_t)S_LEN * 96 * 4);        // 0.75 MB
  short* dtlow  = (short*)alloc((size_t)S_LEN * DTR * 2);       // 0.25 MB
  float* dtbuf  = (float*)alloc((size_t)S_LEN * INNER * 4);     // 16 MB (delta in place)
  float* mambo  = (float*)alloc((size_t)S_LEN * DIM * 4);       // 8 MB
  // aliases (lifetimes disjoint in stream order):
  float* attn_o = q_out;   // q_out dead after qkv_prep
  short* scano  = xsb;     // xs_bf16 dead after xproj gemm
  short* merged = qh;      // qh dead after attention

  dim3 blk(256);
  auto cast = [&](const float* src, short* dst, int n) {
    cast_f2b<<<dim3((n + 255) / 256), blk, 0, stream>>>(src, dst, n);
  };

  // 0. bf16 operand copies
  cast(x, xb, S_LEN * DIM);
  cast(W_cq, Wcq_b, DIM * DIM);
  cast(W_in, Win_b, FUSED_N * DIM);
  cast(W_xproj, Wxp_b, 96 * INNER);
  cast(W_dt, Wdt_b, INNER * DTR);
  cast(W_mout, Wmo_b, DIM * INNER);
  cast(W_proj, Wpr_b, DIM * DIM);

  // 1. q_out = x @ W_cq^T
  gemm_bt<<<dim3(S_LEN / 64, DIM / 64), blk, 0, stream>>>(xb, Wcq_b, q_out, S_LEN, DIM, DIM);
  // 2. fused = x @ W_in^T
  gemm_bt<<<dim3(S_LEN / 64, FUSED_N / 64), blk, 0, stream>>>(xb, Win_b, fusedb, S_LEN, FUSED_N, DIM);
  // 3. q/k/v prep (rms + rope + gain)
  qkv_prep<<<dim3(S_LEN, NH + KVH), dim3(64), 0, stream>>>(q_out, fusedb, q_gain, qh, kh, vh);
  // 4. flash attention
  attn_kernel<<<dim3(S_LEN / 64, NH), blk, 0, stream>>>(qh, kh, vh, attn_o);
  // 5. depthwise conv + silu
  conv_kernel<<<dim3(INNER / 256, S_LEN), blk, 0, stream>>>(fusedb, conv_w, conv_b, xsf, xsb);
  // 6. ssm_params = xs @ W_xproj^T  (N=96, guarded)
  gemm_bt<<<dim3(S_LEN / 64, 2), blk, 0, stream>>>(xsb, Wxp_b, ssmp, S_LEN, 96, INNER);
  // 7. dt_low -> bf16
  cast_dtlow<<<dim3(S_LEN * DTR / 256), blk, 0, stream>>>(ssmp, dtlow);
  // 8. dt = dt_low @ W_dt^T
  gemm_bt<<<dim3(S_LEN / 64, INNER / 64), blk, 0, stream>>>(dtlow, Wdt_b, dtbuf, S_LEN, INNER, DTR);
  // 9. delta = softplus(dt + b_dt), in place
  delta_kernel<<<dim3((S_LEN * INNER) / 256), blk, 0, stream>>>(dtbuf, b_dt);
  // 10. selective scan (+ D term + gate silu) -> bf16
  scan_kernel<<<dim3(INNER / 16), blk, 0, stream>>>(dtbuf, xsf, ssmp, fusedb, A_log, D_param, scano);
  // 11. mamba_out = scan_out @ W_mout^T
  gemm_bt<<<dim3(S_LEN / 64, DIM / 64), blk, 0, stream>>>(scano, Wmo_b, mambo, S_LEN, DIM, INNER);
  // 12. merge
  merge_kernel<<<dim3((S_LEN * DIM) / 256), blk, 0, stream>>>(attn_o, mambo, merge_a, merged);
  // 13. out = merged @ W_proj^T  (fp32 out)
  gemm_bt<<<dim3(S_LEN / 64, DIM / 64), blk, 0, stream>>>(merged, Wpr_b, (float*)d_out, S_LEN, DIM, DIM);
}

// Round 4
// 549.280 us; speedup vs baseline: 1.9937x; 1.9937x over previous
//
#include <hip/hip_runtime.h>
#include <hip/hip_bf16.h>

#define S_LEN 2048
#define DIM   1024
#define NH    16
#define KVH   4
#define HD    64
#define KVDIM 256
#define INNER 2048
#define NSTATE 16
#define DTR   64
#define FUSED_N 4608   // 2*KVDIM + 2*INNER
#define NC    32       // scan chunks
#define CL    64       // chunk length (NC*CL == S_LEN)

typedef __attribute__((ext_vector_type(8))) short short8;
typedef __attribute__((ext_vector_type(4))) float f32x4;
typedef __hip_bfloat16 bf16;

__device__ inline short f2bs(float x) {
  bf16 h = __float2bfloat16(x);
  return *reinterpret_cast<short*>(&h);
}

// ---------------------------------------------------------------------------
// fp32 -> bf16 cast (pre-stage for MFMA operands)
// ---------------------------------------------------------------------------
__global__ __launch_bounds__(256) void cast_f2b(const float* __restrict__ src,
                                                short* __restrict__ dst, int n) {
  int i = blockIdx.x * 256 + threadIdx.x;
  if (i < n) dst[i] = f2bs(src[i]);
}

// ---------------------------------------------------------------------------
// C = A (MxK, bf16 row-major) * B^T (B is NxK bf16 row-major) -> C MxN (fp32)
// 64x64 tile, BK=32, 4 waves of 2x2 16x16x32 MFMA tiles.
// ---------------------------------------------------------------------------
__global__ __launch_bounds__(256) void gemm_bt(const short* __restrict__ A,
                                               const short* __restrict__ B,
                                               float* __restrict__ C,
                                               int M, int N, int K) {
  __shared__ short As[4][64][8];
  __shared__ short Bs[4][64][8];
  const int tid = threadIdx.x;
  const int bm = blockIdx.x * 64;
  const int bn = blockIdx.y * 64;
  const int wid = tid >> 6;
  const int lane = tid & 63;
  const int wm = (wid >> 1) * 32;
  const int wn = (wid & 1) * 32;
  const int m16 = lane & 15;
  const int quad = lane >> 4;
  const int lrow = tid >> 2;
  const int lkq = tid & 3;

  f32x4 acc[2][2];
  #pragma unroll
  for (int i = 0; i < 2; ++i)
    #pragma unroll
    for (int j = 0; j < 2; ++j) acc[i][j] = f32x4{0.f, 0.f, 0.f, 0.f};

  const short* aptr = A + (size_t)(bm + lrow) * K + lkq * 8;
  const bool bvalid = (bn + lrow) < N;
  const short* bptr = B + (size_t)(bn + lrow) * K + lkq * 8;

  for (int k0 = 0; k0 < K; k0 += 32) {
    short8 av = *reinterpret_cast<const short8*>(aptr + k0);
    short8 bv = {0, 0, 0, 0, 0, 0, 0, 0};
    if (bvalid) bv = *reinterpret_cast<const short8*>(bptr + k0);
    __syncthreads();  // previous iteration's LDS reads complete
    *reinterpret_cast<short8*>(&As[lkq][lrow][0]) = av;
    *reinterpret_cast<short8*>(&Bs[lkq][lrow][0]) = bv;
    __syncthreads();
    short8 a0 = *reinterpret_cast<const short8*>(&As[quad][wm + m16][0]);
    short8 a1 = *reinterpret_cast<const short8*>(&As[quad][wm + 16 + m16][0]);
    short8 b0 = *reinterpret_cast<const short8*>(&Bs[quad][wn + m16][0]);
    short8 b1 = *reinterpret_cast<const short8*>(&Bs[quad][wn + 16 + m16][0]);
    acc[0][0] = __builtin_amdgcn_mfma_f32_16x16x32_bf16(a0, b0, acc[0][0], 0, 0, 0);
    acc[0][1] = __builtin_amdgcn_mfma_f32_16x16x32_bf16(a0, b1, acc[0][1], 0, 0, 0);
    acc[1][0] = __builtin_amdgcn_mfma_f32_16x16x32_bf16(a1, b0, acc[1][0], 0, 0, 0);
    acc[1][1] = __builtin_amdgcn_mfma_f32_16x16x32_bf16(a1, b1, acc[1][1], 0, 0, 0);
  }

  // C/D layout: col = lane&15, row = quad*4 + reg
  const int r0 = bm + wm + quad * 4;
  const int c0 = bn + wn + m16;
  #pragma unroll
  for (int ti = 0; ti < 2; ++ti) {
    #pragma unroll
    for (int tj = 0; tj < 2; ++tj) {
      int cc = c0 + tj * 16;
      if (cc >= N) continue;
      #pragma unroll
      for (int i = 0; i < 4; ++i) {
        int rr = r0 + ti * 16 + i;
        C[(size_t)rr * N + cc] = acc[ti][tj][i];
      }
    }
  }
}

// ---------------------------------------------------------------------------
// Per (s, head): RMS norm, RoPE, scale+gain for q. Emits bf16 [head][s][64].
// ---------------------------------------------------------------------------
__global__ __launch_bounds__(64) void qkv_prep(const float* __restrict__ q_out,
                                               const float* __restrict__ fused,
                                               const float* __restrict__ q_gain,
                                               short* __restrict__ qh,
                                               short* __restrict__ kh,
                                               short* __restrict__ vh) {
  const int s = blockIdx.x;
  const int hh = blockIdx.y;
  const int lane = threadIdx.x;

  float val;
  if (hh < NH) val = q_out[(size_t)s * DIM + hh * HD + lane];
  else         val = fused[(size_t)s * FUSED_N + (hh - NH) * HD + lane];

  float sq = val * val;
  #pragma unroll
  for (int off = 32; off >= 1; off >>= 1) sq += __shfl_xor(sq, off);
  float r = rsqrtf(sq * (1.0f / 64.0f) + 1.1920929e-07f);
  float v2 = val * r;

  float partner = __shfl_xor(v2, 16);
  if (lane < 32) {
    int fi = lane & 15;
    float inv = expf(-(float)fi * (9.210340371976184f / 16.0f));
    float ang = (float)s * inv;
    float sn, c;
    sincosf(ang, &sn, &c);
    v2 = (lane < 16) ? (v2 * c + partner * sn) : (v2 * c - partner * sn);
  }

  if (hh < NH) {
    v2 *= 0.125f * q_gain[hh];
    qh[((size_t)hh * S_LEN + s) * HD + lane] = f2bs(v2);
  } else {
    int kv = hh - NH;
    kh[((size_t)kv * S_LEN + s) * HD + lane] = f2bs(v2);
    float vv = fused[(size_t)s * FUSED_N + KVDIM + kv * HD + lane];
    vh[((size_t)kv * S_LEN + s) * HD + lane] = f2bs(vv);
  }
}

// ---------------------------------------------------------------------------
// Flash attention, MFMA. Block = 64 q-rows of one head; 4 waves x 16 rows.
// ---------------------------------------------------------------------------
__global__ __launch_bounds__(256) void attn_kernel(const short* __restrict__ qh,
                                                   const short* __restrict__ kh,
                                                   const short* __restrict__ vh,
                                                   float* __restrict__ attn_out) {
  __shared__ short Ks[32][72];
  __shared__ short Vt[64][40];
  __shared__ short Ps[4][16][40];

  const int tid = threadIdx.x;
  const int wv = tid >> 6;
  const int lane = tid & 63;
  const int qt = blockIdx.x;
  const int h = blockIdx.y;
  const int kvh = h >> 2;
  const int m16 = lane & 15;
  const int quad = lane >> 4;
  const int qrow0 = qt * 64 + wv * 16;

  const short* qptr = qh + ((size_t)h * S_LEN + qrow0 + m16) * HD;
  short8 qf0 = *reinterpret_cast<const short8*>(qptr + quad * 8);
  short8 qf1 = *reinterpret_cast<const short8*>(qptr + 32 + quad * 8);

  f32x4 o[4];
  float mrow[4], lrow[4];
  #pragma unroll
  for (int i = 0; i < 4; ++i) {
    o[i] = f32x4{0.f, 0.f, 0.f, 0.f};
    mrow[i] = -1e30f;
    lrow[i] = 0.f;
  }

  const int ntiles = qt * 2 + 2;
  const int ldr = tid >> 3;
  const int ldc = (tid & 7) * 8;
  const short* kbase = kh + (size_t)kvh * S_LEN * HD;
  const short* vbase = vh + (size_t)kvh * S_LEN * HD;

  for (int jt = 0; jt < ntiles; ++jt) {
    const int key0 = jt * 32;
    short8 kv8 = *reinterpret_cast<const short8*>(kbase + (size_t)(key0 + ldr) * HD + ldc);
    short8 vv8 = *reinterpret_cast<const short8*>(vbase + (size_t)(key0 + ldr) * HD + ldc);
    __syncthreads();
    *reinterpret_cast<short8*>(&Ks[ldr][ldc]) = kv8;
    #pragma unroll
    for (int i = 0; i < 8; ++i) Vt[ldc + i][ldr] = vv8[i];
    __syncthreads();

    f32x4 sc[2];
    #pragma unroll
    for (int sub = 0; sub < 2; ++sub) {
      short8 kf0 = *reinterpret_cast<const short8*>(&Ks[sub * 16 + m16][quad * 8]);
      short8 kf1 = *reinterpret_cast<const short8*>(&Ks[sub * 16 + m16][32 + quad * 8]);
      f32x4 z = f32x4{0.f, 0.f, 0.f, 0.f};
      z = __builtin_amdgcn_mfma_f32_16x16x32_bf16(qf0, kf0, z, 0, 0, 0);
      z = __builtin_amdgcn_mfma_f32_16x16x32_bf16(qf1, kf1, z, 0, 0, 0);
      sc[sub] = z;
    }

    #pragma unroll
    for (int i = 0; i < 4; ++i) {
      const int qpos = qrow0 + quad * 4 + i;
      float s0 = (key0 + m16 <= qpos) ? sc[0][i] : -1e30f;
      float s1 = (key0 + 16 + m16 <= qpos) ? sc[1][i] : -1e30f;
      float rm = fmaxf(s0, s1);
      rm = fmaxf(rm, __shfl_xor(rm, 1));
      rm = fmaxf(rm, __shfl_xor(rm, 2));
      rm = fmaxf(rm, __shfl_xor(rm, 4));
      rm = fmaxf(rm, __shfl_xor(rm, 8));
      float mnew = fmaxf(mrow[i], rm);
      float alpha = __expf(mrow[i] - mnew);
      float p0 = __expf(s0 - mnew);
      float p1 = __expf(s1 - mnew);
      float rs = p0 + p1;
      rs += __shfl_xor(rs, 1);
      rs += __shfl_xor(rs, 2);
      rs += __shfl_xor(rs, 4);
      rs += __shfl_xor(rs, 8);
      lrow[i] = lrow[i] * alpha + rs;
      mrow[i] = mnew;
      #pragma unroll
      for (int nc = 0; nc < 4; ++nc) o[nc][i] *= alpha;
      Ps[wv][quad * 4 + i][m16] = f2bs(p0);
      Ps[wv][quad * 4 + i][16 + m16] = f2bs(p1);
    }
    __syncthreads();

    short8 af = *reinterpret_cast<const short8*>(&Ps[wv][m16][quad * 8]);
    #pragma unroll
    for (int nc = 0; nc < 4; ++nc) {
      short8 bfv = *reinterpret_cast<const short8*>(&Vt[nc * 16 + m16][quad * 8]);
      o[nc] = __builtin_amdgcn_mfma_f32_16x16x32_bf16(af, bfv, o[nc], 0, 0, 0);
    }
  }

  #pragma unroll
  for (int i = 0; i < 4; ++i) {
    float inv_l = 1.0f / lrow[i];
    int rr = qrow0 + quad * 4 + i;
    #pragma unroll
    for (int nc = 0; nc < 4; ++nc)
      attn_out[(size_t)rr * DIM + h * HD + nc * 16 + m16] = o[nc][i] * inv_l;
  }
}

// ---------------------------------------------------------------------------
// Depthwise causal conv (K=4) + bias + SiLU.
// ---------------------------------------------------------------------------
__global__ __launch_bounds__(256) void conv_kernel(const float* __restrict__ fused,
                                                   const float* __restrict__ conv_w,
                                                   const float* __restrict__ conv_b,
                                                   float* __restrict__ xs_f32,
                                                   short* __restrict__ xs_b) {
  const int c = blockIdx.x * 256 + threadIdx.x;
  const int s = blockIdx.y;
  float acc = conv_b[c];
  #pragma unroll
  for (int t = 0; t < 4; ++t) {
    int sp = s - 3 + t;
    if (sp >= 0)
      acc += fused[(size_t)sp * FUSED_N + 2 * KVDIM + c] * conv_w[c * 4 + t];
  }
  float sv = acc / (1.f + __expf(-acc));
  xs_f32[(size_t)s * INNER + c] = sv;
  xs_b[(size_t)s * INNER + c] = f2bs(sv);
}

__global__ __launch_bounds__(256) void cast_dtlow(const float* __restrict__ ssm,
                                                  short* __restrict__ dtlow) {
  const int i = blockIdx.x * 256 + threadIdx.x;
  const int row = i >> 6, col = i & 63;
  dtlow[i] = f2bs(ssm[(size_t)row * 96 + col]);
}

__global__ __launch_bounds__(256) void delta_kernel(float* __restrict__ dt,
                                                    const float* __restrict__ b_dt) {
  const size_t i = (size_t)blockIdx.x * 256 + threadIdx.x;
  const int dcol = (int)(i & (INNER - 1));
  float xv = dt[i] + b_dt[dcol];
  dt[i] = (xv > 20.f) ? xv : log1pf(__expf(xv));
}

// ---------------------------------------------------------------------------
// Chunked parallel selective scan.
// p1: per (chunk, d-block) run recurrence from h=0 -> chunk-end state hE and
//     per-chunk sum of delta (chunk decay = exp(A * sum_delta)).
// p2: serial combine over NC chunks per (d,n) -> chunk-initial states hI.
// p3: rerun each chunk from hI; emit y with D-term + gate SiLU.
// ---------------------------------------------------------------------------
__global__ __launch_bounds__(256) void scan_p1(const float* __restrict__ delta,
                                               const float* __restrict__ xs,
                                               const float* __restrict__ ssm,
                                               const float* __restrict__ A_log,
                                               float* __restrict__ hE,
                                               float* __restrict__ sdel) {
  __shared__ float Ld[64][16], Lu[64][16], Lb[64][16];
  const int tid = threadIdx.x;
  const int nl = tid & 15;
  const int dl = tid >> 4;
  const int d0 = blockIdx.x * 16;
  const int d = d0 + dl;
  const int c = blockIdx.y;
  const int t0 = c * CL;
  const float Aa = -__expf(A_log[(size_t)d * NSTATE + nl]);

  #pragma unroll
  for (int rep = 0; rep < 4; ++rep) {
    int f = tid + rep * 256;
    int sl = f >> 4, dc = f & 15;
    int sg = t0 + sl;
    Ld[sl][dc] = delta[(size_t)sg * INNER + d0 + dc];
    Lu[sl][dc] = xs[(size_t)sg * INNER + d0 + dc];
    Lb[sl][dc] = ssm[(size_t)sg * 96 + DTR + dc];
  }
  __syncthreads();

  float h = 0.f, sd = 0.f;
  for (int sl = 0; sl < CL; ++sl) {
    float dlt = Ld[sl][dl];
    float u = Lu[sl][dl];
    float Bv = Lb[sl][nl];
    h = __expf(dlt * Aa) * h + (dlt * u) * Bv;
    sd += dlt;
  }
  hE[((size_t)c * INNER + d) * NSTATE + nl] = h;
  if (nl == 0) sdel[(size_t)c * INNER + d] = sd;
}

__global__ __launch_bounds__(256) void scan_p2(const float* __restrict__ hE,
                                               const float* __restrict__ sdel,
                                               const float* __restrict__ A_log,
                                               float* __restrict__ hI) {
  const int idx = blockIdx.x * 256 + threadIdx.x;  // < INNER*NSTATE
  const int d = idx >> 4, n = idx & 15;
  const float Aa = -__expf(A_log[(size_t)d * NSTATE + n]);
  float h = 0.f;
  for (int c = 0; c < NC; ++c) {
    hI[((size_t)c * INNER + d) * NSTATE + n] = h;
    float aP = __expf(Aa * sdel[(size_t)c * INNER + d]);
    h = aP * h + hE[((size_t)c * INNER + d) * NSTATE + n];
  }
}

__global__ __launch_bounds__(256) void scan_p3(const float* __restrict__ delta,
                                               const float* __restrict__ xs,
                                               const float* __restrict__ ssm,
                                               const float* __restrict__ fused,
                                               const float* __restrict__ A_log,
                                               const float* __restrict__ D_param,
                                               const float* __restrict__ hI,
                                               short* __restrict__ scan_out) {
  __shared__ float Ld[64][16], Lu[64][16], Lg[64][16], Lb[64][16], Lc[64][16];
  const int tid = threadIdx.x;
  const int nl = tid & 15;
  const int dl = tid >> 4;
  const int d0 = blockIdx.x * 16;
  const int d = d0 + dl;
  const int c = blockIdx.y;
  const int t0 = c * CL;
  const float Aa = -__expf(A_log[(size_t)d * NSTATE + nl]);
  const float Dp = D_param[d];

  #pragma unroll
  for (int rep = 0; rep < 4; ++rep) {
    int f = tid + rep * 256;
    int sl = f >> 4, dc = f & 15;
    int sg = t0 + sl;
    Ld[sl][dc] = delta[(size_t)sg * INNER + d0 + dc];
    Lu[sl][dc] = xs[(size_t)sg * INNER + d0 + dc];
    Lg[sl][dc] = fused[(size_t)sg * FUSED_N + 2 * KVDIM + INNER + d0 + dc];
    Lb[sl][dc] = ssm[(size_t)sg * 96 + DTR + dc];
    Lc[sl][dc] = ssm[(size_t)sg * 96 + DTR + NSTATE + dc];
  }
  __syncthreads();

  float h = hI[((size_t)c * INNER + d) * NSTATE + nl];
  for (int sl = 0; sl < CL; ++sl) {
    float dlt = Ld[sl][dl];
    float u = Lu[sl][dl];
    float Bv = Lb[sl][nl];
    float Cv = Lc[sl][nl];
    h = __expf(dlt * Aa) * h + (dlt * u) * Bv;
    float t = h * Cv;
    t += __shfl_xor(t, 1);
    t += __shfl_xor(t, 2);
    t += __shfl_xor(t, 4);
    t += __shfl_xor(t, 8);
    if (nl == 0) {
      float g = Lg[sl][dl];
      float scv = (t + u * Dp) * (g / (1.f + __expf(-g)));
      scan_out[(size_t)(t0 + sl) * INNER + d] = f2bs(scv);
    }
  }
}

__global__ __launch_bounds__(256) void merge_kernel(const float* __restrict__ attn_out,
                                                    const float* __restrict__ mamba_out,
                                                    const float* __restrict__ merge_alpha,
                                                    short* __restrict__ merged) {
  const size_t i = (size_t)blockIdx.x * 256 + threadIdx.x;
  float a = merge_alpha[0];
  float w = 1.f / (1.f + __expf(-a));
  merged[i] = f2bs(w * attn_out[i] + (1.f - w) * mamba_out[i]);
}

// ---------------------------------------------------------------------------
extern "C" void kernel_launch(void* const* d_in, const int* in_sizes, int n_in,
                              void* d_out, int out_size, void* d_ws, size_t ws_size,
                              hipStream_t stream) {
  const float* x       = (const float*)d_in[0];
  const float* W_cq    = (const float*)d_in[1];
  const float* W_in    = (const float*)d_in[2];
  const float* q_gain  = (const float*)d_in[3];
  const float* conv_w  = (const float*)d_in[4];
  const float* conv_b  = (const float*)d_in[5];
  const float* W_xproj = (const float*)d_in[6];
  const float* W_dt    = (const float*)d_in[7];
  const float* b_dt    = (const float*)d_in[8];
  const float* A_log   = (const float*)d_in[9];
  const float* D_param = (const float*)d_in[10];
  const float* W_mout  = (const float*)d_in[11];
  const float* W_proj  = (const float*)d_in[12];
  const float* merge_a = (const float*)d_in[13];

  char* p = (char*)d_ws;
  auto alloc = [&](size_t bytes) {
    char* r = p;
    p += (bytes + 255) & ~(size_t)255;
    return r;
  };
  // bf16 copies of MFMA operands
  short* xb     = (short*)alloc((size_t)S_LEN * DIM * 2);
  short* Wcq_b  = (short*)alloc((size_t)DIM * DIM * 2);
  short* Win_b  = (short*)alloc((size_t)FUSED_N * DIM * 2);
  short* Wxp_b  = (short*)alloc((size_t)96 * INNER * 2);
  short* Wdt_b  = (short*)alloc((size_t)INNER * DTR * 2);
  short* Wmo_b  = (short*)alloc((size_t)DIM * INNER * 2);
  short* Wpr_b  = (short*)alloc((size_t)DIM * DIM * 2);
  // fp32 intermediates
  float* q_out  = (float*)alloc((size_t)S_LEN * DIM * 4);
  float* fusedb = (float*)alloc((size_t)S_LEN * FUSED_N * 4);
  short* qh     = (short*)alloc((size_t)NH * S_LEN * HD * 2);
  short* kh     = (short*)alloc((size_t)KVH * S_LEN * HD * 2);
  short* vh     = (short*)alloc((size_t)KVH * S_LEN * HD * 2);
  float* xsf    = (float*)alloc((size_t)S_LEN * INNER * 4);
  short* xsb    = (short*)alloc((size_t)S_LEN * INNER * 2);
  float* ssmp   = (float*)alloc((size_t)S_LEN * 96 * 4);
  short* dtlow  = (short*)alloc((size_t)S_LEN * DTR * 2);
  float* dtbuf  = (float*)alloc((size_t)S_LEN * INNER * 4);
  float* mambo  = (float*)alloc((size_t)S_LEN * DIM * 4);
  // scan chunk aggregates
  float* hE     = (float*)alloc((size_t)NC * INNER * NSTATE * 4);  // 4 MB
  float* sdel   = (float*)alloc((size_t)NC * INNER * 4);           // 0.25 MB
  float* hI     = (float*)alloc((size_t)NC * INNER * NSTATE * 4);  // 4 MB
  // aliases (lifetimes disjoint in stream order):
  float* attn_o = q_out;   // q_out dead after qkv_prep
  short* scano  = xsb;     // xs_bf16 dead after xproj gemm
  short* merged = qh;      // qh dead after attention

  dim3 blk(256);
  auto cast = [&](const float* src, short* dst, int n) {
    cast_f2b<<<dim3((n + 255) / 256), blk, 0, stream>>>(src, dst, n);
  };

  // 0. bf16 operand copies
  cast(x, xb, S_LEN * DIM);
  cast(W_cq, Wcq_b, DIM * DIM);
  cast(W_in, Win_b, FUSED_N * DIM);
  cast(W_xproj, Wxp_b, 96 * INNER);
  cast(W_dt, Wdt_b, INNER * DTR);
  cast(W_mout, Wmo_b, DIM * INNER);
  cast(W_proj, Wpr_b, DIM * DIM);

  // 1. q_out = x @ W_cq^T
  gemm_bt<<<dim3(S_LEN / 64, DIM / 64), blk, 0, stream>>>(xb, Wcq_b, q_out, S_LEN, DIM, DIM);
  // 2. fused = x @ W_in^T
  gemm_bt<<<dim3(S_LEN / 64, FUSED_N / 64), blk, 0, stream>>>(xb, Win_b, fusedb, S_LEN, FUSED_N, DIM);
  // 3. q/k/v prep
  qkv_prep<<<dim3(S_LEN, NH + KVH), dim3(64), 0, stream>>>(q_out, fusedb, q_gain, qh, kh, vh);
  // 4. flash attention
  attn_kernel<<<dim3(S_LEN / 64, NH), blk, 0, stream>>>(qh, kh, vh, attn_o);
  // 5. depthwise conv + silu
  conv_kernel<<<dim3(INNER / 256, S_LEN), blk, 0, stream>>>(fusedb, conv_w, conv_b, xsf, xsb);
  // 6. ssm_params = xs @ W_xproj^T
  gemm_bt<<<dim3(S_LEN / 64, 2), blk, 0, stream>>>(xsb, Wxp_b, ssmp, S_LEN, 96, INNER);
  // 7. dt_low -> bf16
  cast_dtlow<<<dim3(S_LEN * DTR / 256), blk, 0, stream>>>(ssmp, dtlow);
  // 8. dt = dt_low @ W_dt^T
  gemm_bt<<<dim3(S_LEN / 64, INNER / 64), blk, 0, stream>>>(dtlow, Wdt_b, dtbuf, S_LEN, INNER, DTR);
  // 9. delta = softplus(dt + b_dt), in place
  delta_kernel<<<dim3((S_LEN * INNER) / 256), blk, 0, stream>>>(dtbuf, b_dt);
  // 10. chunked selective scan
  scan_p1<<<dim3(INNER / 16, NC), blk, 0, stream>>>(dtbuf, xsf, ssmp, A_log, hE, sdel);
  scan_p2<<<dim3(INNER * NSTATE / 256), blk, 0, stream>>>(hE, sdel, A_log, hI);
  scan_p3<<<dim3(INNER / 16, NC), blk, 0, stream>>>(dtbuf, xsf, ssmp, fusedb, A_log, D_param, hI, scano);
  // 11. mamba_out = scan_out @ W_mout^T
  gemm_bt<<<dim3(S_LEN / 64, DIM / 64), blk, 0, stream>>>(scano, Wmo_b, mambo, S_LEN, DIM, INNER);
  // 12. merge
  merge_kernel<<<dim3((S_LEN * DIM) / 256), blk, 0, stream>>>(attn_o, mambo, merge_a, merged);
  // 13. out = merged @ W_proj^T
  gemm_bt<<<dim3(S_LEN / 64, DIM / 64), blk, 0, stream>>>(merged, Wpr_b, (float*)d_out, S_LEN, DIM, DIM);
}

// Round 5
// 544.040 us; speedup vs baseline: 2.0129x; 1.0096x over previous
//
#include <hip/hip_runtime.h>
#include <hip/hip_bf16.h>

#define S_LEN 2048
#define DIM   1024
#define NH    16
#define KVH   4
#define HD    64
#define KVDIM 256
#define INNER 2048
#define NSTATE 16
#define DTR   64
#define FUSED_N 4608   // 2*KVDIM + 2*INNER
#define NC    32       // scan chunks
#define CL    64       // chunk length (NC*CL == S_LEN)

typedef __attribute__((ext_vector_type(8))) short short8;
typedef __attribute__((ext_vector_type(4))) float f32x4;
typedef __hip_bfloat16 bf16;

__device__ inline short f2bs(float x) {
  bf16 h = __float2bfloat16(x);
  return *reinterpret_cast<short*>(&h);
}
__device__ inline unsigned pack2(float a, float b) {
  unsigned lo = (unsigned)(unsigned short)f2bs(a);
  unsigned hi = (unsigned)(unsigned short)f2bs(b);
  return lo | (hi << 16);
}

// ---------------------------------------------------------------------------
// fp32 -> bf16 cast (pre-stage for MFMA operands)
// ---------------------------------------------------------------------------
__global__ __launch_bounds__(256) void cast_f2b(const float* __restrict__ src,
                                                short* __restrict__ dst, int n) {
  int i = blockIdx.x * 256 + threadIdx.x;
  if (i < n) dst[i] = f2bs(src[i]);
}

// ---------------------------------------------------------------------------
// C = A (MxK, bf16 row-major) * B^T (B is NxK bf16 row-major) -> C MxN (fp32)
// 64x64 tile, BK=32, 4 waves of 2x2 16x16x32 MFMA tiles.
// ---------------------------------------------------------------------------
__global__ __launch_bounds__(256) void gemm_bt(const short* __restrict__ A,
                                               const short* __restrict__ B,
                                               float* __restrict__ C,
                                               int M, int N, int K) {
  __shared__ short As[4][64][8];
  __shared__ short Bs[4][64][8];
  const int tid = threadIdx.x;
  const int bm = blockIdx.x * 64;
  const int bn = blockIdx.y * 64;
  const int wid = tid >> 6;
  const int lane = tid & 63;
  const int wm = (wid >> 1) * 32;
  const int wn = (wid & 1) * 32;
  const int m16 = lane & 15;
  const int quad = lane >> 4;
  const int lrow = tid >> 2;
  const int lkq = tid & 3;

  f32x4 acc[2][2];
  #pragma unroll
  for (int i = 0; i < 2; ++i)
    #pragma unroll
    for (int j = 0; j < 2; ++j) acc[i][j] = f32x4{0.f, 0.f, 0.f, 0.f};

  const short* aptr = A + (size_t)(bm + lrow) * K + lkq * 8;
  const bool bvalid = (bn + lrow) < N;
  const short* bptr = B + (size_t)(bn + lrow) * K + lkq * 8;

  for (int k0 = 0; k0 < K; k0 += 32) {
    short8 av = *reinterpret_cast<const short8*>(aptr + k0);
    short8 bv = {0, 0, 0, 0, 0, 0, 0, 0};
    if (bvalid) bv = *reinterpret_cast<const short8*>(bptr + k0);
    __syncthreads();
    *reinterpret_cast<short8*>(&As[lkq][lrow][0]) = av;
    *reinterpret_cast<short8*>(&Bs[lkq][lrow][0]) = bv;
    __syncthreads();
    short8 a0 = *reinterpret_cast<const short8*>(&As[quad][wm + m16][0]);
    short8 a1 = *reinterpret_cast<const short8*>(&As[quad][wm + 16 + m16][0]);
    short8 b0 = *reinterpret_cast<const short8*>(&Bs[quad][wn + m16][0]);
    short8 b1 = *reinterpret_cast<const short8*>(&Bs[quad][wn + 16 + m16][0]);
    acc[0][0] = __builtin_amdgcn_mfma_f32_16x16x32_bf16(a0, b0, acc[0][0], 0, 0, 0);
    acc[0][1] = __builtin_amdgcn_mfma_f32_16x16x32_bf16(a0, b1, acc[0][1], 0, 0, 0);
    acc[1][0] = __builtin_amdgcn_mfma_f32_16x16x32_bf16(a1, b0, acc[1][0], 0, 0, 0);
    acc[1][1] = __builtin_amdgcn_mfma_f32_16x16x32_bf16(a1, b1, acc[1][1], 0, 0, 0);
  }

  const int r0 = bm + wm + quad * 4;
  const int c0 = bn + wn + m16;
  #pragma unroll
  for (int ti = 0; ti < 2; ++ti) {
    #pragma unroll
    for (int tj = 0; tj < 2; ++tj) {
      int cc = c0 + tj * 16;
      if (cc >= N) continue;
      #pragma unroll
      for (int i = 0; i < 4; ++i) {
        int rr = r0 + ti * 16 + i;
        C[(size_t)rr * N + cc] = acc[ti][tj][i];
      }
    }
  }
}

// ---------------------------------------------------------------------------
// Per (s, head): RMS norm, RoPE, scale+gain for q. Emits bf16 [head][s][64];
// V additionally transposed to [kvh][dim][s] for direct B-fragment loads.
// ---------------------------------------------------------------------------
__global__ __launch_bounds__(64) void qkv_prep(const float* __restrict__ q_out,
                                               const float* __restrict__ fused,
                                               const float* __restrict__ q_gain,
                                               short* __restrict__ qh,
                                               short* __restrict__ kh,
                                               short* __restrict__ vt) {
  const int s = blockIdx.x;
  const int hh = blockIdx.y;
  const int lane = threadIdx.x;

  float val;
  if (hh < NH) val = q_out[(size_t)s * DIM + hh * HD + lane];
  else         val = fused[(size_t)s * FUSED_N + (hh - NH) * HD + lane];

  float sq = val * val;
  #pragma unroll
  for (int off = 32; off >= 1; off >>= 1) sq += __shfl_xor(sq, off);
  float r = rsqrtf(sq * (1.0f / 64.0f) + 1.1920929e-07f);
  float v2 = val * r;

  float partner = __shfl_xor(v2, 16);
  if (lane < 32) {
    int fi = lane & 15;
    float inv = expf(-(float)fi * (9.210340371976184f / 16.0f));
    float ang = (float)s * inv;
    float sn, c;
    sincosf(ang, &sn, &c);
    v2 = (lane < 16) ? (v2 * c + partner * sn) : (v2 * c - partner * sn);
  }

  if (hh < NH) {
    v2 *= 0.125f * q_gain[hh];
    qh[((size_t)hh * S_LEN + s) * HD + lane] = f2bs(v2);
  } else {
    int kv = hh - NH;
    kh[((size_t)kv * S_LEN + s) * HD + lane] = f2bs(v2);
    float vv = fused[(size_t)s * FUSED_N + KVDIM + kv * HD + lane];
    vt[((size_t)kv * HD + lane) * S_LEN + s] = f2bs(vv);  // transposed
  }
}

// ---------------------------------------------------------------------------
// Flash attention, MFMA, barrier-free. Block = 4 independent waves, each
// owning 16 q-rows. K/V fragments loaded directly from global (K row-major
// == B-operand layout; V pre-transposed). P round-trips through per-wave LDS
// (packed b32 writes, 40-short rows: 16B-aligned b128 reads, <=2-way banks).
// Sub-tile interleave: lane m16 owns keys {key0+2*m16, key0+2*m16+1}.
// ---------------------------------------------------------------------------
__global__ __launch_bounds__(256) void attn_kernel(const short* __restrict__ qh,
                                                   const short* __restrict__ kh,
                                                   const short* __restrict__ vt,
                                                   float* __restrict__ attn_out) {
  __shared__ short Ps[4][16][40];   // per-wave P: 16 rows x 32 keys, 80B rows

  const int tid = threadIdx.x;
  const int wv = tid >> 6;
  const int lane = tid & 63;
  const int qt = gridDim.x - 1 - blockIdx.x;  // big tiles dispatch first
  const int h = blockIdx.y;
  const int kvh = h >> 2;
  const int m16 = lane & 15;
  const int quad = lane >> 4;
  const int qrow0 = qt * 64 + wv * 16;

  // Q fragments: A-operand layout A[m=lane&15][k=quad*8+j]
  const short* qptr = qh + ((size_t)h * S_LEN + qrow0 + m16) * HD;
  short8 qf0 = *reinterpret_cast<const short8*>(qptr + quad * 8);
  short8 qf1 = *reinterpret_cast<const short8*>(qptr + 32 + quad * 8);

  f32x4 o[4];
  float mrow[4], lrow[4];
  #pragma unroll
  for (int i = 0; i < 4; ++i) {
    o[i] = f32x4{0.f, 0.f, 0.f, 0.f};
    mrow[i] = -1e30f;
    lrow[i] = 0.f;
  }

  const int ntiles = (qrow0 + 15) / 32 + 1;   // per-wave trip count
  const short* kbase = kh + (size_t)kvh * S_LEN * HD;
  const short* vbase = vt + (size_t)kvh * HD * S_LEN;

  for (int jt = 0; jt < ntiles; ++jt) {
    const int key0 = jt * 32;
    // K fragments straight from global: key = key0 + 2*m16 + sub
    const short* kp0 = kbase + (size_t)(key0 + 2 * m16) * HD + quad * 8;
    short8 k00 = *reinterpret_cast<const short8*>(kp0);
    short8 k01 = *reinterpret_cast<const short8*>(kp0 + 32);
    short8 k10 = *reinterpret_cast<const short8*>(kp0 + HD);
    short8 k11 = *reinterpret_cast<const short8*>(kp0 + HD + 32);

    f32x4 sc0 = f32x4{0.f, 0.f, 0.f, 0.f};
    sc0 = __builtin_amdgcn_mfma_f32_16x16x32_bf16(qf0, k00, sc0, 0, 0, 0);
    sc0 = __builtin_amdgcn_mfma_f32_16x16x32_bf16(qf1, k01, sc0, 0, 0, 0);
    f32x4 sc1 = f32x4{0.f, 0.f, 0.f, 0.f};
    sc1 = __builtin_amdgcn_mfma_f32_16x16x32_bf16(qf0, k10, sc1, 0, 0, 0);
    sc1 = __builtin_amdgcn_mfma_f32_16x16x32_bf16(qf1, k11, sc1, 0, 0, 0);

    // online softmax (C layout: row = quad*4+i, this lane's keys 2*m16,+1)
    #pragma unroll
    for (int i = 0; i < 4; ++i) {
      const int qpos = qrow0 + quad * 4 + i;
      const int kcol = key0 + 2 * m16;
      float s0 = (kcol <= qpos) ? sc0[i] : -1e30f;
      float s1 = (kcol + 1 <= qpos) ? sc1[i] : -1e30f;
      float rm = fmaxf(s0, s1);
      rm = fmaxf(rm, __shfl_xor(rm, 1));
      rm = fmaxf(rm, __shfl_xor(rm, 2));
      rm = fmaxf(rm, __shfl_xor(rm, 4));
      rm = fmaxf(rm, __shfl_xor(rm, 8));
      float mnew = fmaxf(mrow[i], rm);
      float alpha = __expf(mrow[i] - mnew);
      float p0 = __expf(s0 - mnew);
      float p1 = __expf(s1 - mnew);
      lrow[i] = lrow[i] * alpha + p0 + p1;  // per-lane partial sum
      mrow[i] = mnew;
      #pragma unroll
      for (int nc = 0; nc < 4; ++nc) o[nc][i] *= alpha;
      *reinterpret_cast<unsigned*>(&Ps[wv][quad * 4 + i][2 * m16]) = pack2(p0, p1);
    }

    // PV: P as A-operand (per-wave LDS round trip, in-order per wave)
    short8 af = *reinterpret_cast<const short8*>(&Ps[wv][m16][quad * 8]);
    #pragma unroll
    for (int nc = 0; nc < 4; ++nc) {
      const short* vp = vbase + (size_t)(nc * 16 + m16) * S_LEN + key0 + quad * 8;
      short8 bfv = *reinterpret_cast<const short8*>(vp);
      o[nc] = __builtin_amdgcn_mfma_f32_16x16x32_bf16(af, bfv, o[nc], 0, 0, 0);
    }
  }

  #pragma unroll
  for (int i = 0; i < 4; ++i) {
    float ls = lrow[i];
    ls += __shfl_xor(ls, 1);
    ls += __shfl_xor(ls, 2);
    ls += __shfl_xor(ls, 4);
    ls += __shfl_xor(ls, 8);
    float inv_l = 1.0f / ls;
    int rr = qrow0 + quad * 4 + i;
    #pragma unroll
    for (int nc = 0; nc < 4; ++nc)
      attn_out[(size_t)rr * DIM + h * HD + nc * 16 + m16] = o[nc][i] * inv_l;
  }
}

// ---------------------------------------------------------------------------
// Depthwise causal conv (K=4) + bias + SiLU.
// ---------------------------------------------------------------------------
__global__ __launch_bounds__(256) void conv_kernel(const float* __restrict__ fused,
                                                   const float* __restrict__ conv_w,
                                                   const float* __restrict__ conv_b,
                                                   float* __restrict__ xs_f32,
                                                   short* __restrict__ xs_b) {
  const int c = blockIdx.x * 256 + threadIdx.x;
  const int s = blockIdx.y;
  float acc = conv_b[c];
  #pragma unroll
  for (int t = 0; t < 4; ++t) {
    int sp = s - 3 + t;
    if (sp >= 0)
      acc += fused[(size_t)sp * FUSED_N + 2 * KVDIM + c] * conv_w[c * 4 + t];
  }
  float sv = acc / (1.f + __expf(-acc));
  xs_f32[(size_t)s * INNER + c] = sv;
  xs_b[(size_t)s * INNER + c] = f2bs(sv);
}

__global__ __launch_bounds__(256) void cast_dtlow(const float* __restrict__ ssm,
                                                  short* __restrict__ dtlow) {
  const int i = blockIdx.x * 256 + threadIdx.x;
  const int row = i >> 6, col = i & 63;
  dtlow[i] = f2bs(ssm[(size_t)row * 96 + col]);
}

__global__ __launch_bounds__(256) void delta_kernel(float* __restrict__ dt,
                                                    const float* __restrict__ b_dt) {
  const size_t i = (size_t)blockIdx.x * 256 + threadIdx.x;
  const int dcol = (int)(i & (INNER - 1));
  float xv = dt[i] + b_dt[dcol];
  dt[i] = (xv > 20.f) ? xv : log1pf(__expf(xv));
}

// ---------------------------------------------------------------------------
// Chunked parallel selective scan (p1: chunk-local, p2: combine, p3: replay).
// ---------------------------------------------------------------------------
__global__ __launch_bounds__(256) void scan_p1(const float* __restrict__ delta,
                                               const float* __restrict__ xs,
                                               const float* __restrict__ ssm,
                                               const float* __restrict__ A_log,
                                               float* __restrict__ hE,
                                               float* __restrict__ sdel) {
  __shared__ float Ld[64][16], Lu[64][16], Lb[64][16];
  const int tid = threadIdx.x;
  const int nl = tid & 15;
  const int dl = tid >> 4;
  const int d0 = blockIdx.x * 16;
  const int d = d0 + dl;
  const int c = blockIdx.y;
  const int t0 = c * CL;
  const float Aa = -__expf(A_log[(size_t)d * NSTATE + nl]);

  #pragma unroll
  for (int rep = 0; rep < 4; ++rep) {
    int f = tid + rep * 256;
    int sl = f >> 4, dc = f & 15;
    int sg = t0 + sl;
    Ld[sl][dc] = delta[(size_t)sg * INNER + d0 + dc];
    Lu[sl][dc] = xs[(size_t)sg * INNER + d0 + dc];
    Lb[sl][dc] = ssm[(size_t)sg * 96 + DTR + dc];
  }
  __syncthreads();

  float h = 0.f, sd = 0.f;
  for (int sl = 0; sl < CL; ++sl) {
    float dlt = Ld[sl][dl];
    float u = Lu[sl][dl];
    float Bv = Lb[sl][nl];
    h = __expf(dlt * Aa) * h + (dlt * u) * Bv;
    sd += dlt;
  }
  hE[((size_t)c * INNER + d) * NSTATE + nl] = h;
  if (nl == 0) sdel[(size_t)c * INNER + d] = sd;
}

__global__ __launch_bounds__(256) void scan_p2(const float* __restrict__ hE,
                                               const float* __restrict__ sdel,
                                               const float* __restrict__ A_log,
                                               float* __restrict__ hI) {
  const int idx = blockIdx.x * 256 + threadIdx.x;  // < INNER*NSTATE
  const int d = idx >> 4, n = idx & 15;
  const float Aa = -__expf(A_log[(size_t)d * NSTATE + n]);
  float h = 0.f;
  for (int c = 0; c < NC; ++c) {
    hI[((size_t)c * INNER + d) * NSTATE + n] = h;
    float aP = __expf(Aa * sdel[(size_t)c * INNER + d]);
    h = aP * h + hE[((size_t)c * INNER + d) * NSTATE + n];
  }
}

__global__ __launch_bounds__(256) void scan_p3(const float* __restrict__ delta,
                                               const float* __restrict__ xs,
                                               const float* __restrict__ ssm,
                                               const float* __restrict__ fused,
                                               const float* __restrict__ A_log,
                                               const float* __restrict__ D_param,
                                               const float* __restrict__ hI,
                                               short* __restrict__ scan_out) {
  __shared__ float Ld[64][16], Lu[64][16], Lg[64][16], Lb[64][16], Lc[64][16];
  const int tid = threadIdx.x;
  const int nl = tid & 15;
  const int dl = tid >> 4;
  const int d0 = blockIdx.x * 16;
  const int d = d0 + dl;
  const int c = blockIdx.y;
  const int t0 = c * CL;
  const float Aa = -__expf(A_log[(size_t)d * NSTATE + nl]);
  const float Dp = D_param[d];

  #pragma unroll
  for (int rep = 0; rep < 4; ++rep) {
    int f = tid + rep * 256;
    int sl = f >> 4, dc = f & 15;
    int sg = t0 + sl;
    Ld[sl][dc] = delta[(size_t)sg * INNER + d0 + dc];
    Lu[sl][dc] = xs[(size_t)sg * INNER + d0 + dc];
    Lg[sl][dc] = fused[(size_t)sg * FUSED_N + 2 * KVDIM + INNER + d0 + dc];
    Lb[sl][dc] = ssm[(size_t)sg * 96 + DTR + dc];
    Lc[sl][dc] = ssm[(size_t)sg * 96 + DTR + NSTATE + dc];
  }
  __syncthreads();

  float h = hI[((size_t)c * INNER + d) * NSTATE + nl];
  for (int sl = 0; sl < CL; ++sl) {
    float dlt = Ld[sl][dl];
    float u = Lu[sl][dl];
    float Bv = Lb[sl][nl];
    float Cv = Lc[sl][nl];
    h = __expf(dlt * Aa) * h + (dlt * u) * Bv;
    float t = h * Cv;
    t += __shfl_xor(t, 1);
    t += __shfl_xor(t, 2);
    t += __shfl_xor(t, 4);
    t += __shfl_xor(t, 8);
    if (nl == 0) {
      float g = Lg[sl][dl];
      float scv = (t + u * Dp) * (g / (1.f + __expf(-g)));
      scan_out[(size_t)(t0 + sl) * INNER + d] = f2bs(scv);
    }
  }
}

__global__ __launch_bounds__(256) void merge_kernel(const float* __restrict__ attn_out,
                                                    const float* __restrict__ mamba_out,
                                                    const float* __restrict__ merge_alpha,
                                                    short* __restrict__ merged) {
  const size_t i = (size_t)blockIdx.x * 256 + threadIdx.x;
  float a = merge_alpha[0];
  float w = 1.f / (1.f + __expf(-a));
  merged[i] = f2bs(w * attn_out[i] + (1.f - w) * mamba_out[i]);
}

// ---------------------------------------------------------------------------
extern "C" void kernel_launch(void* const* d_in, const int* in_sizes, int n_in,
                              void* d_out, int out_size, void* d_ws, size_t ws_size,
                              hipStream_t stream) {
  const float* x       = (const float*)d_in[0];
  const float* W_cq    = (const float*)d_in[1];
  const float* W_in    = (const float*)d_in[2];
  const float* q_gain  = (const float*)d_in[3];
  const float* conv_w  = (const float*)d_in[4];
  const float* conv_b  = (const float*)d_in[5];
  const float* W_xproj = (const float*)d_in[6];
  const float* W_dt    = (const float*)d_in[7];
  const float* b_dt    = (const float*)d_in[8];
  const float* A_log   = (const float*)d_in[9];
  const float* D_param = (const float*)d_in[10];
  const float* W_mout  = (const float*)d_in[11];
  const float* W_proj  = (const float*)d_in[12];
  const float* merge_a = (const float*)d_in[13];

  char* p = (char*)d_ws;
  auto alloc = [&](size_t bytes) {
    char* r = p;
    p += (bytes + 255) & ~(size_t)255;
    return r;
  };
  // bf16 copies of MFMA operands
  short* xb     = (short*)alloc((size_t)S_LEN * DIM * 2);
  short* Wcq_b  = (short*)alloc((size_t)DIM * DIM * 2);
  short* Win_b  = (short*)alloc((size_t)FUSED_N * DIM * 2);
  short* Wxp_b  = (short*)alloc((size_t)96 * INNER * 2);
  short* Wdt_b  = (short*)alloc((size_t)INNER * DTR * 2);
  short* Wmo_b  = (short*)alloc((size_t)DIM * INNER * 2);
  short* Wpr_b  = (short*)alloc((size_t)DIM * DIM * 2);
  // fp32 intermediates
  float* q_out  = (float*)alloc((size_t)S_LEN * DIM * 4);
  float* fusedb = (float*)alloc((size_t)S_LEN * FUSED_N * 4);
  short* qh     = (short*)alloc((size_t)NH * S_LEN * HD * 2);
  short* kh     = (short*)alloc((size_t)KVH * S_LEN * HD * 2);
  short* vtb    = (short*)alloc((size_t)KVH * S_LEN * HD * 2);
  float* xsf    = (float*)alloc((size_t)S_LEN * INNER * 4);
  short* xsb    = (short*)alloc((size_t)S_LEN * INNER * 2);
  float* ssmp   = (float*)alloc((size_t)S_LEN * 96 * 4);
  short* dtlow  = (short*)alloc((size_t)S_LEN * DTR * 2);
  float* dtbuf  = (float*)alloc((size_t)S_LEN * INNER * 4);
  float* mambo  = (float*)alloc((size_t)S_LEN * DIM * 4);
  // scan chunk aggregates
  float* hE     = (float*)alloc((size_t)NC * INNER * NSTATE * 4);
  float* sdel   = (float*)alloc((size_t)NC * INNER * 4);
  float* hI     = (float*)alloc((size_t)NC * INNER * NSTATE * 4);
  // aliases (lifetimes disjoint in stream order):
  float* attn_o = q_out;   // q_out dead after qkv_prep
  short* scano  = xsb;     // xs_bf16 dead after xproj gemm
  short* merged = qh;      // qh dead after attention

  dim3 blk(256);
  auto cast = [&](const float* src, short* dst, int n) {
    cast_f2b<<<dim3((n + 255) / 256), blk, 0, stream>>>(src, dst, n);
  };

  // 0. bf16 operand copies
  cast(x, xb, S_LEN * DIM);
  cast(W_cq, Wcq_b, DIM * DIM);
  cast(W_in, Win_b, FUSED_N * DIM);
  cast(W_xproj, Wxp_b, 96 * INNER);
  cast(W_dt, Wdt_b, INNER * DTR);
  cast(W_mout, Wmo_b, DIM * INNER);
  cast(W_proj, Wpr_b, DIM * DIM);

  // 1. q_out = x @ W_cq^T
  gemm_bt<<<dim3(S_LEN / 64, DIM / 64), blk, 0, stream>>>(xb, Wcq_b, q_out, S_LEN, DIM, DIM);
  // 2. fused = x @ W_in^T
  gemm_bt<<<dim3(S_LEN / 64, FUSED_N / 64), blk, 0, stream>>>(xb, Win_b, fusedb, S_LEN, FUSED_N, DIM);
  // 3. q/k/v prep
  qkv_prep<<<dim3(S_LEN, NH + KVH), dim3(64), 0, stream>>>(q_out, fusedb, q_gain, qh, kh, vtb);
  // 4. flash attention (barrier-free)
  attn_kernel<<<dim3(S_LEN / 64, NH), blk, 0, stream>>>(qh, kh, vtb, attn_o);
  // 5. depthwise conv + silu
  conv_kernel<<<dim3(INNER / 256, S_LEN), blk, 0, stream>>>(fusedb, conv_w, conv_b, xsf, xsb);
  // 6. ssm_params = xs @ W_xproj^T
  gemm_bt<<<dim3(S_LEN / 64, 2), blk, 0, stream>>>(xsb, Wxp_b, ssmp, S_LEN, 96, INNER);
  // 7. dt_low -> bf16
  cast_dtlow<<<dim3(S_LEN * DTR / 256), blk, 0, stream>>>(ssmp, dtlow);
  // 8. dt = dt_low @ W_dt^T
  gemm_bt<<<dim3(S_LEN / 64, INNER / 64), blk, 0, stream>>>(dtlow, Wdt_b, dtbuf, S_LEN, INNER, DTR);
  // 9. delta = softplus(dt + b_dt), in place
  delta_kernel<<<dim3((S_LEN * INNER) / 256), blk, 0, stream>>>(dtbuf, b_dt);
  // 10. chunked selective scan
  scan_p1<<<dim3(INNER / 16, NC), blk, 0, stream>>>(dtbuf, xsf, ssmp, A_log, hE, sdel);
  scan_p2<<<dim3(INNER * NSTATE / 256), blk, 0, stream>>>(hE, sdel, A_log, hI);
  scan_p3<<<dim3(INNER / 16, NC), blk, 0, stream>>>(dtbuf, xsf, ssmp, fusedb, A_log, D_param, hI, scano);
  // 11. mamba_out = scan_out @ W_mout^T
  gemm_bt<<<dim3(S_LEN / 64, DIM / 64), blk, 0, stream>>>(scano, Wmo_b, mambo, S_LEN, DIM, INNER);
  // 12. merge
  merge_kernel<<<dim3((S_LEN * DIM) / 256), blk, 0, stream>>>(attn_o, mambo, merge_a, merged);
  // 13. out = merged @ W_proj^T
  gemm_bt<<<dim3(S_LEN / 64, DIM / 64), blk, 0, stream>>>(merged, Wpr_b, (float*)d_out, S_LEN, DIM, DIM);
}